// Round 9
// baseline (262.298 us; speedup 1.0000x reference)
//
#include <hip/hip_runtime.h>
#include <hip/hip_bf16.h>
#include <stdint.h>

typedef unsigned short u16;
typedef unsigned int u32;
typedef __attribute__((ext_vector_type(8))) short short8;
typedef __attribute__((ext_vector_type(4))) float f32x4;

#define T_TOK 2048
#define H_DIM 1024
#define F_DIM 4096
#define E_NUM 8
#define M_SLOT 4096
#define KSPLIT 4

__device__ __forceinline__ u16 f2bf(float f){
  union { float f; u32 u; } v; v.f = f;
  return (u16)((v.u + 0x7FFFu + ((v.u >> 16) & 1u)) >> 16);
}

__device__ __forceinline__ void gload_lds16(const void* g, void* l){
  __builtin_amdgcn_global_load_lds(
      (const __attribute__((address_space(1))) u32*)g,
      (__attribute__((address_space(3))) u32*)l, 16, 0, 0);
}

// ---------------- router: logits = x @ rw, top2, softmax ----------------
__global__ __launch_bounds__(256) void router_kernel(
    const float* __restrict__ x, const float* __restrict__ rw,
    int* __restrict__ tok_e, float* __restrict__ tok_p){
  __shared__ float wlds[E_NUM * H_DIM];
  int tid = threadIdx.x;
  for (int i = tid; i < H_DIM * E_NUM; i += 256){
    int h = i >> 3, e = i & 7;
    wlds[e * H_DIM + h] = rw[i];
  }
  __syncthreads();
  int wave = tid >> 6, lane = tid & 63;
  int t = blockIdx.x * 4 + wave;
  const float* xr = x + (size_t)t * H_DIM;
  float acc[E_NUM];
  #pragma unroll
  for (int e = 0; e < E_NUM; e++) acc[e] = 0.f;
  for (int i = 0; i < H_DIM / 64; i++){
    float xv = xr[lane + 64 * i];
    #pragma unroll
    for (int e = 0; e < E_NUM; e++) acc[e] += xv * wlds[e * H_DIM + lane + 64 * i];
  }
  #pragma unroll
  for (int e = 0; e < E_NUM; e++){
    float r = acc[e];
    #pragma unroll
    for (int off = 32; off; off >>= 1) r += __shfl_xor(r, off, 64);
    acc[e] = r;
  }
  if (lane == 0){
    float l0 = acc[0]; int e0 = 0;
    #pragma unroll
    for (int e = 1; e < E_NUM; e++) if (acc[e] > l0){ l0 = acc[e]; e0 = e; }
    float l1 = -INFINITY; int e1 = 0;
    #pragma unroll
    for (int e = 0; e < E_NUM; e++) if (e != e0 && acc[e] > l1){ l1 = acc[e]; e1 = e; }
    float ex = expf(l1 - l0);
    float inv = 1.f / (1.f + ex);
    tok_e[2*t] = e0; tok_e[2*t+1] = e1;
    tok_p[2*t] = inv; tok_p[2*t+1] = ex * inv;
  }
}

// ---------------- histogram ----------------
__global__ void hist_kernel(const int* __restrict__ tok_e, u32* __restrict__ partial){
  int lane = threadIdx.x & 63;
  int m = blockIdx.x * 64 + lane;
  int e = tok_e[m];
  #pragma unroll
  for (int ee = 0; ee < E_NUM; ee++){
    unsigned long long mk = __ballot(e == ee);
    if (lane == ee) partial[blockIdx.x * E_NUM + ee] = (u32)__popcll(mk);
  }
}

// ---------------- scan: chunk bases + expert offsets/counts ----------------
__global__ void scan_kernel(const u32* __restrict__ partial, u32* __restrict__ baseb,
                            int* __restrict__ eoffs, int* __restrict__ ecnt){
  int lane = threadIdx.x;  // 64 threads
  u32 exc[E_NUM], tot[E_NUM];
  #pragma unroll
  for (int e = 0; e < E_NUM; e++){
    u32 v = partial[lane * E_NUM + e];
    u32 own = v;
    #pragma unroll
    for (int off = 1; off < 64; off <<= 1){
      u32 tu = __shfl_up(v, off, 64);
      if (lane >= off) v += tu;
    }
    exc[e] = v - own;
    tot[e] = __shfl(v, 63, 64);
  }
  u32 offs[E_NUM + 1]; offs[0] = 0;
  #pragma unroll
  for (int e = 0; e < E_NUM; e++) offs[e+1] = offs[e] + tot[e];
  #pragma unroll
  for (int e = 0; e < E_NUM; e++) baseb[lane * E_NUM + e] = offs[e] + exc[e];
  if (lane == 0){
    #pragma unroll
    for (int e = 0; e < E_NUM; e++){ eoffs[e] = (int)offs[e]; ecnt[e] = (int)tot[e]; }
  }
}

// ---------------- scatter ----------------
__global__ void scatter_kernel(const int* __restrict__ tok_e, const u32* __restrict__ baseb,
                               int* __restrict__ dest){
  int lane = threadIdx.x & 63;
  int m = blockIdx.x * 64 + lane;
  int e = tok_e[m];
  unsigned long long eq = 0;
  #pragma unroll
  for (int ee = 0; ee < E_NUM; ee++){
    unsigned long long mk = __ballot(e == ee);
    if (e == ee) eq = mk;
  }
  u32 rank = (u32)__popcll(eq & ((1ull << lane) - 1ull));
  dest[m] = (int)(baseb[blockIdx.x * E_NUM + e] + rank);
}

// ---------------- gather ----------------
__global__ __launch_bounds__(256) void gather_kernel(const float* __restrict__ x,
                                                     const int* __restrict__ dest,
                                                     u16* __restrict__ xg){
  int m = blockIdx.x;
  int d = dest[m];
  const float4* xr = (const float4*)(x + (size_t)(m >> 1) * H_DIM);
  float4 v = xr[threadIdx.x];
  ushort4 o;
  o.x = f2bf(v.x); o.y = f2bf(v.y); o.z = f2bf(v.z); o.w = f2bf(v.w);
  ((ushort4*)(xg + (size_t)d * H_DIM))[threadIdx.x] = o;
}

// ---------------- fused persistent-strip grouped GEMM ----------------
// Block = (expert e = blockIdx.y, 64-col strip = blockIdx.x, K-split z).
// A [*][AK] bf16 row-major (xg or gb). W [E][AK][WN] f32 ORIGINAL layout.
// Per K-chunk (256): stage W f32 [64k][64n] sub-tiles -> in-LDS cvt ->
// Bs [64 n][4 ks][64 k] bf16 swizzled; Bs resident across the whole M-loop,
// so each weight byte is read from HBM exactly once chip-wide.
// M-loop: up to 5 static 128-row tiles per group (acc0..acc4 statically named,
// rule #20), A double-buffered via the proven r5 gload+swizzle path.
// NF = n-frags per wave = 2 (wave grid 2x2 over 128x64 tile).
template<int WN, int AK, int NCHUNK, bool GELU_EP>
__global__ __launch_bounds__(256, 2) void gemmfs(
    const u16* __restrict__ A, const float* __restrict__ W,
    const int* __restrict__ eoffs, const int* __restrict__ ecnt,
    float* __restrict__ outF, u16* __restrict__ outB, size_t zstride){
  constexpr int NF = 2;
  __shared__ __align__(16) u16 As[2][128 * 64];   // 32 KB
  __shared__ __align__(16) u16 Bs[64 * 256];      // 32 KB: [n][ks][k] swizzled
  __shared__ __align__(16) float Bf[64 * 64];     // 16 KB: raw f32 [k][n]

  int tid = threadIdx.x, lane = tid & 63, wid = tid >> 6;
  int wr = wid >> 1, wc = wid & 1;
  int e = blockIdx.y;
  int col0 = blockIdx.x * 64;
  int kbase0 = blockIdx.z * (NCHUNK * 256);
  const float* We = W + (size_t)e * AK * WN;
  float* outFz = outF + (size_t)blockIdx.z * zstride;
  int row0e = eoffs[e], cnt = ecnt[e];
  int skx = ((lane & 7) * 16) ^ ((lane >> 3) << 4);

  auto stageA = [&](int r0t, int kg, int p){
    #pragma unroll
    for (int i = 0; i < 4; i++){
      int row = i * 32 + (wid << 3) + (lane >> 3);
      gload_lds16((const char*)(A + (size_t)(r0t + row) * AK + kg) + skx,
                  (char*)&As[p][0] + i * 4096 + wid * 1024);
    }
  };

  auto stageB = [&](int kc){
    #pragma unroll
    for (int sub = 0; sub < 4; sub++){
      int kg = kbase0 + kc * 256 + sub * 64;
      #pragma unroll
      for (int i = 0; i < 4; i++){
        const char* src = (const char*)(We + (size_t)(kg + i * 16 + (tid >> 4)) * WN + col0)
                          + (tid & 15) * 16;
        gload_lds16(src, (char*)Bf + i * 4096 + tid * 16);
      }
      __syncthreads();                 // vmcnt(0) drain + publish Bf
      if (tid < 128){
        int rb = tid & 7, cb = tid >> 3;   // cb 0..15
        float f[8][4];
        #pragma unroll
        for (int j = 0; j < 8; j++)
          *(float4*)&f[j][0] = *(const float4*)((const char*)Bf + (rb * 8 + j) * 256 + cb * 16);
        #pragma unroll
        for (int i2 = 0; i2 < 4; i2++){
          int n = cb * 4 + i2;
          short8 v;
          #pragma unroll
          for (int j = 0; j < 8; j++) v[j] = (short)f2bf(f[j][i2]);
          *(short8*)((char*)Bs + n * 512 + sub * 128 + ((rb * 16) ^ ((n & 7) << 4))) = v;
        }
      }
      __syncthreads();                 // Bs sub published; Bf reusable
    }
  };

#define STEPM(ACC, P, KS) do{ \
  _Pragma("unroll") \
  for (int kk = 0; kk < 2; kk++){ \
    short8 a_[4], b_[NF]; \
    _Pragma("unroll") \
    for (int m = 0; m < 4; m++){ \
      int row = wr * 64 + m * 16 + (lane & 15); \
      int by = row * 128 + ((kk * 64 + (lane >> 4) * 16) ^ ((row & 7) << 4)); \
      a_[m] = *(const short8*)((const char*)&As[P][0] + by); } \
    _Pragma("unroll") \
    for (int nf = 0; nf < NF; nf++){ \
      int row = wc * 32 + nf * 16 + (lane & 15); \
      int by = row * 512 + (KS) * 128 + ((kk * 64 + (lane >> 4) * 16) ^ ((row & 7) << 4)); \
      b_[nf] = *(const short8*)((const char*)Bs + by); } \
    _Pragma("unroll") \
    for (int m = 0; m < 4; m++) \
      _Pragma("unroll") \
      for (int nf = 0; nf < NF; nf++) \
        ACC[m][nf] = __builtin_amdgcn_mfma_f32_16x16x32_bf16(a_[m], b_[nf], ACC[m][nf], 0, 0, 0); \
  } }while(0)

#define TILEKC(ACC, MT) do{ if ((MT) * 128 < vrows){ \
  int r0t = row0e + g0 + (MT) * 128; \
  stageA(r0t, kg0, 0); __syncthreads(); \
  _Pragma("unroll") \
  for (int ks = 0; ks < 4; ks++){ \
    if (ks < 3) stageA(r0t, kg0 + (ks + 1) * 64, (ks + 1) & 1); \
    STEPM(ACC, (ks & 1), ks); \
    __syncthreads(); \
  } } }while(0)

#define EPIM(ACC, MT) do{ if ((MT) * 128 < vrows){ \
  int nr = vrows - (MT) * 128; if (nr > 128) nr = 128; \
  int r0t = row0e + g0 + (MT) * 128; \
  _Pragma("unroll") \
  for (int m = 0; m < 4; m++){ \
    int rloc = wr * 64 + m * 16 + (lane >> 4) * 4; \
    _Pragma("unroll") \
    for (int j = 0; j < 4; j++){ \
      int rr = rloc + j; \
      if (rr < nr){ \
        size_t rowg = (size_t)(r0t + rr); \
        _Pragma("unroll") \
        for (int nf = 0; nf < NF; nf++){ \
          int cc = col0 + wc * 32 + nf * 16 + (lane & 15); \
          float v = ACC[m][nf][j]; \
          if (GELU_EP){ \
            float g = v * 0.5f * (1.f + erff(v * 0.70710678118f)); \
            outFz[rowg * WN + cc] = g; \
            outB[rowg * WN + cc] = f2bf(g); \
          } else { \
            outFz[rowg * WN + cc] = v; \
          } \
        } } } } } }while(0)

#define ZEROM(ACC) do{ \
  _Pragma("unroll") \
  for (int m = 0; m < 4; m++) \
    _Pragma("unroll") \
    for (int nf = 0; nf < NF; nf++) ACC[m][nf] = (f32x4)0.f; }while(0)

  f32x4 acc0[4][NF], acc1[4][NF], acc2[4][NF], acc3[4][NF], acc4[4][NF];

  for (int g0 = 0; g0 < cnt; g0 += 640){
    int vrows = cnt - g0; if (vrows > 640) vrows = 640;
    ZEROM(acc0); ZEROM(acc1); ZEROM(acc2); ZEROM(acc3); ZEROM(acc4);
    for (int kc = 0; kc < NCHUNK; kc++){
      int kg0 = kbase0 + kc * 256;
      stageB(kc);
      TILEKC(acc0, 0); TILEKC(acc1, 1); TILEKC(acc2, 2); TILEKC(acc3, 3); TILEKC(acc4, 4);
    }
    EPIM(acc0, 0); EPIM(acc1, 1); EPIM(acc2, 2); EPIM(acc3, 3); EPIM(acc4, 4);
  }
#undef STEPM
#undef TILEKC
#undef EPIM
#undef ZEROM
}

// ---------------- combine: sum KSPLIT partials, weighted ----------------
__global__ __launch_bounds__(256) void combine_kernel(const float* __restrict__ yp,
                                                      const int* __restrict__ dest,
                                                      const float* __restrict__ tok_p,
                                                      float* __restrict__ out){
  int t = blockIdx.x;
  int d0 = dest[2*t], d1 = dest[2*t+1];
  float p0 = tok_p[2*t], p1 = tok_p[2*t+1];
  float4 r; r.x = 0.f; r.y = 0.f; r.z = 0.f; r.w = 0.f;
  #pragma unroll
  for (int s = 0; s < KSPLIT; s++){
    float4 a = ((const float4*)(yp + ((size_t)s * M_SLOT + d0) * H_DIM))[threadIdx.x];
    float4 b = ((const float4*)(yp + ((size_t)s * M_SLOT + d1) * H_DIM))[threadIdx.x];
    r.x += p0*a.x + p1*b.x; r.y += p0*a.y + p1*b.y;
    r.z += p0*a.z + p1*b.z; r.w += p0*a.w + p1*b.w;
  }
  ((float4*)(out + (size_t)t * H_DIM))[threadIdx.x] = r;
}

extern "C" void kernel_launch(void* const* d_in, const int* in_sizes, int n_in,
                              void* d_out, int out_size, void* d_ws, size_t ws_size,
                              hipStream_t stream) {
  const float* x  = (const float*)d_in[0];
  const float* rw = (const float*)d_in[1];
  const float* w1 = (const float*)d_in[2];
  const float* w2 = (const float*)d_in[3];
  float* out_mlp  = (float*)d_out;
  float* out_gelu = (float*)d_out + (size_t)T_TOK * H_DIM;

  char* ws = (char*)d_ws;
  u16*   xg    = (u16*)(ws + 0);                     // [M+768][1024] bf16 (~10 MB)
  u16*   gb    = (u16*)(ws + (10u << 20));           // [M+768][4096] bf16 (~40 MB)
  float* ypart = (float*)(ws + (50u << 20));         // [4][M][1024] f32 (67 MB)
  char*  small = ws + (120u << 20);
  int*   tok_e = (int*)(small);
  float* tok_p = (float*)(small + 16384);
  int*   dest  = (int*)(small + 32768);
  u32*   partial = (u32*)(small + 49152);
  u32*   baseb   = (u32*)(small + 51200);
  int*   eoffs   = (int*)(small + 53248);
  int*   ecnt    = (int*)(small + 53504);

  router_kernel<<<T_TOK/4, 256, 0, stream>>>(x, rw, tok_e, tok_p);
  hist_kernel<<<M_SLOT/64, 64, 0, stream>>>(tok_e, partial);
  scan_kernel<<<1, 64, 0, stream>>>(partial, baseb, eoffs, ecnt);
  scatter_kernel<<<M_SLOT/64, 64, 0, stream>>>(tok_e, baseb, dest);
  gather_kernel<<<M_SLOT, 256, 0, stream>>>(x, dest, xg);
  // GEMM1F: [M,1024] @ w1[e] (f32 [1024][4096], direct) + GELU
  //   grid: 64 strips x 8 experts = 512 blocks, 2/CU
  gemmfs<F_DIM, H_DIM, 4, true><<<dim3(F_DIM/64, E_NUM, 1), 256, 0, stream>>>(
      xg, w1, eoffs, ecnt, out_gelu, gb, 0);
  // GEMM2F: [M,4096] @ w2[e] (f32 [4096][1024], direct), split-K=4
  //   grid: 16 strips x 8 experts x 4 splits = 512 blocks, 2/CU
  gemmfs<H_DIM, F_DIM, 4, false><<<dim3(H_DIM/64, E_NUM, KSPLIT), 256, 0, stream>>>(
      gb, w2, eoffs, ecnt, ypart, nullptr, (size_t)M_SLOT * H_DIM);
  combine_kernel<<<T_TOK, 256, 0, stream>>>(ypart, dest, tok_p, out_mlp);
}

// Round 10
// 251.063 us; speedup vs baseline: 1.0448x; 1.0448x over previous
//
#include <hip/hip_runtime.h>
#include <hip/hip_bf16.h>
#include <stdint.h>

typedef unsigned short u16;
typedef unsigned int u32;
typedef __attribute__((ext_vector_type(8))) short short8;
typedef __attribute__((ext_vector_type(4))) float f32x4;

#define T_TOK 2048
#define H_DIM 1024
#define F_DIM 4096
#define E_NUM 8
#define M_SLOT 4096
#define MAXTILES 24
#define KSPLIT 2

__device__ __forceinline__ u16 f2bf(float f){
  union { float f; u32 u; } v; v.f = f;
  return (u16)((v.u + 0x7FFFu + ((v.u >> 16) & 1u)) >> 16);
}

__device__ __forceinline__ void gload_lds16(const void* g, void* l){
  __builtin_amdgcn_global_load_lds(
      (const __attribute__((address_space(1))) u32*)g,
      (__attribute__((address_space(3))) u32*)l, 16, 0, 0);
}

// raw barrier -- NO sched_barrier(0) fences (m141 lesson: order-pinning kills
// the compiler's intra-phase interleave of ds_read/addr-calc/stg with MFMA)
#define BARRIER() __builtin_amdgcn_s_barrier()
#define VMC6() asm volatile("s_waitcnt vmcnt(6)" ::: "memory")
#define VMC0() asm volatile("s_waitcnt vmcnt(0)" ::: "memory")

// ---------------- router ----------------
__global__ __launch_bounds__(256) void router_kernel(
    const float* __restrict__ x, const float* __restrict__ rw,
    int* __restrict__ tok_e, float* __restrict__ tok_p){
  __shared__ float wlds[E_NUM * H_DIM];
  int tid = threadIdx.x;
  for (int i = tid; i < H_DIM * E_NUM; i += 256){
    int h = i >> 3, e = i & 7;
    wlds[e * H_DIM + h] = rw[i];
  }
  __syncthreads();
  int wave = tid >> 6, lane = tid & 63;
  int t = blockIdx.x * 4 + wave;
  const float* xr = x + (size_t)t * H_DIM;
  float acc[E_NUM];
  #pragma unroll
  for (int e = 0; e < E_NUM; e++) acc[e] = 0.f;
  for (int i = 0; i < H_DIM / 64; i++){
    float xv = xr[lane + 64 * i];
    #pragma unroll
    for (int e = 0; e < E_NUM; e++) acc[e] += xv * wlds[e * H_DIM + lane + 64 * i];
  }
  #pragma unroll
  for (int e = 0; e < E_NUM; e++){
    float r = acc[e];
    #pragma unroll
    for (int off = 32; off; off >>= 1) r += __shfl_xor(r, off, 64);
    acc[e] = r;
  }
  if (lane == 0){
    float l0 = acc[0]; int e0 = 0;
    #pragma unroll
    for (int e = 1; e < E_NUM; e++) if (acc[e] > l0){ l0 = acc[e]; e0 = e; }
    float l1 = -INFINITY; int e1 = 0;
    #pragma unroll
    for (int e = 0; e < E_NUM; e++) if (e != e0 && acc[e] > l1){ l1 = acc[e]; e1 = e; }
    float ex = expf(l1 - l0);
    float inv = 1.f / (1.f + ex);
    tok_e[2*t] = e0; tok_e[2*t+1] = e1;
    tok_p[2*t] = inv; tok_p[2*t+1] = ex * inv;
  }
}

// ---------------- histogram ----------------
__global__ void hist_kernel(const int* __restrict__ tok_e, u32* __restrict__ partial){
  int lane = threadIdx.x & 63;
  int m = blockIdx.x * 64 + lane;
  int e = tok_e[m];
  #pragma unroll
  for (int ee = 0; ee < E_NUM; ee++){
    unsigned long long mk = __ballot(e == ee);
    if (lane == ee) partial[blockIdx.x * E_NUM + ee] = (u32)__popcll(mk);
  }
}

// ---------------- scan + tile table (256-row tiles) ----------------
__global__ void scan_kernel(const u32* __restrict__ partial, u32* __restrict__ baseb,
                            int4* __restrict__ tiles, int* __restrict__ ntiles){
  int lane = threadIdx.x;  // 64 threads
  u32 exc[E_NUM], tot[E_NUM];
  #pragma unroll
  for (int e = 0; e < E_NUM; e++){
    u32 v = partial[lane * E_NUM + e];
    u32 own = v;
    #pragma unroll
    for (int off = 1; off < 64; off <<= 1){
      u32 tu = __shfl_up(v, off, 64);
      if (lane >= off) v += tu;
    }
    exc[e] = v - own;
    tot[e] = __shfl(v, 63, 64);
  }
  u32 offs[E_NUM + 1]; offs[0] = 0;
  #pragma unroll
  for (int e = 0; e < E_NUM; e++) offs[e+1] = offs[e] + tot[e];
  #pragma unroll
  for (int e = 0; e < E_NUM; e++) baseb[lane * E_NUM + e] = offs[e] + exc[e];
  if (lane == 0){
    int nt = 0;
    for (int e = 0; e < E_NUM; e++){
      int cnt = (int)tot[e];
      for (int r0 = 0; r0 < cnt; r0 += 256){
        tiles[nt] = make_int4((int)offs[e] + r0, min(256, cnt - r0), e, 0);
        nt++;
      }
    }
    *ntiles = nt;
  }
}

// ---------------- scatter ----------------
__global__ void scatter_kernel(const int* __restrict__ tok_e, const u32* __restrict__ baseb,
                               int* __restrict__ dest){
  int lane = threadIdx.x & 63;
  int m = blockIdx.x * 64 + lane;
  int e = tok_e[m];
  unsigned long long eq = 0;
  #pragma unroll
  for (int ee = 0; ee < E_NUM; ee++){
    unsigned long long mk = __ballot(e == ee);
    if (e == ee) eq = mk;
  }
  u32 rank = (u32)__popcll(eq & ((1ull << lane) - 1ull));
  dest[m] = (int)(baseb[blockIdx.x * E_NUM + e] + rank);
}

// ---------------- gather ----------------
__global__ __launch_bounds__(256) void gather_kernel(const float* __restrict__ x,
                                                     const int* __restrict__ dest,
                                                     u16* __restrict__ xg){
  int m = blockIdx.x;
  int d = dest[m];
  const float4* xr = (const float4*)(x + (size_t)(m >> 1) * H_DIM);
  float4 v = xr[threadIdx.x];
  ushort4 o;
  o.x = f2bf(v.x); o.y = f2bf(v.y); o.z = f2bf(v.z); o.w = f2bf(v.w);
  ((ushort4*)(xg + (size_t)d * H_DIM))[threadIdx.x] = o;
}

// ---------------- transpose + fp32->bf16: [E][R][C] -> [E][C][R] ----------------
template<int R, int C>
__global__ __launch_bounds__(256) void transpose_cvt(const float* __restrict__ in,
                                                     u16* __restrict__ out){
  int e = blockIdx.z;
  const float* ip = in + (size_t)e * R * C;
  u16* op = out + (size_t)e * R * C;
  __shared__ u16 tile[64][66];
  int c0 = blockIdx.x * 64, r0 = blockIdx.y * 64;
  int tr = threadIdx.x >> 4, tc = threadIdx.x & 15;
  #pragma unroll
  for (int i = 0; i < 4; i++){
    int r = tr + i * 16;
    float4 v = *(const float4*)(ip + (size_t)(r0 + r) * C + c0 + tc * 4);
    tile[r][tc*4+0] = f2bf(v.x); tile[r][tc*4+1] = f2bf(v.y);
    tile[r][tc*4+2] = f2bf(v.z); tile[r][tc*4+3] = f2bf(v.w);
  }
  __syncthreads();
  #pragma unroll
  for (int i = 0; i < 4; i++){
    int c = tr + i * 16;
    ushort4 o;
    o.x = tile[tc*4+0][c]; o.y = tile[tc*4+1][c];
    o.z = tile[tc*4+2][c]; o.w = tile[tc*4+3][c];
    *(ushort4*)(op + (size_t)(c0 + c) * R + r0 + tc * 4) = o;
  }
}

// ---------------- grouped GEMM, 256x256, 8-phase, lag-3 staging ----------
// Identical to round-8 (which passed; invariants re-verified) EXCEPT the
// sched_barrier(0) fences around s_barrier are removed (m141 lesson).
template<int N, int KSTRIDE, int NT, bool GELU_EP>
__global__ __launch_bounds__(512, 2) void gemm8(
    const u16* __restrict__ A, const u16* __restrict__ Bt,
    const int4* __restrict__ tiles, const int* __restrict__ ntiles_p,
    float* __restrict__ outF, u16* __restrict__ outB, size_t zstride){
  if ((int)blockIdx.y >= *ntiles_p) return;
  int4 ti = tiles[blockIdx.y];
  int row0 = ti.x, nrows = ti.y, e = ti.z;
  int col0 = blockIdx.x * 256;
  size_t kofs = (size_t)blockIdx.z * ((size_t)NT * 64);
  const u16* Be = Bt + (size_t)e * N * KSTRIDE;
  float* outFz = outF + (size_t)blockIdx.z * zstride;

  __shared__ __align__(16) u16 lds[2][4][128 * 64];

  int tid = threadIdx.x, lane = tid & 63, wid = tid >> 6;
  int wrow = wid >> 2, wcol = wid & 3;

  auto stg = [&](int p, int half, int kt){
    const u16* gb_; int rb;
    if (half < 2){ gb_ = A;  rb = row0 + half * 128; }
    else         { gb_ = Be; rb = col0 + (half - 2) * 128; }
    #pragma unroll
    for (int j = 0; j < 2; j++){
      int crow = j * 64 + wid * 8 + (lane >> 3);
      int cb = ((lane & 7) * 16) ^ ((lane >> 3) << 4);
      const char* g = (const char*)(gb_ + (size_t)(rb + crow) * KSTRIDE + kofs + (size_t)kt * 64) + cb;
      u16* l = (u16*)&lds[p][half][0] + (size_t)(j * 512 + wid * 64) * 8;
      gload_lds16(g, l);
    }
  };

  auto frd = [&](int p, int half, int rb16, int kk)->short8{
    int row = rb16 + (lane & 15);
    int byte_ = row * 128 + ((kk * 64 + (lane >> 4) * 16) ^ ((lane & 7) << 4));
    return *(const short8*)((const char*)&lds[p][half][0] + byte_);
  };

  f32x4 acc[8][4];
  #pragma unroll
  for (int m = 0; m < 8; m++)
    #pragma unroll
    for (int n = 0; n < 4; n++) acc[m][n] = (f32x4)0.f;

  short8 a[4][2], b[4][2];

  // prologue: steady-state issue-order roles
  stg(0, 0, 0); stg(0, 3, 0); stg(0, 1, 0); stg(0, 2, 0);   // A0,B1,A1,B0 of t0
  stg(1, 0, 1); stg(1, 3, 1); stg(1, 1, 1);                 // A0,B1,A1 of t1
  VMC6();            // oldest 8 loads landed = all of tile 0
  BARRIER();

  constexpr int NI = NT / 2;
  for (int i = 0; i < NI; i++){
    int te = 2 * i, to = 2 * i + 1;
    bool pre = (i + 1 < NI);
    // ---------- ph1: Q00 even (reads A0,B0 of buf0)
    #pragma unroll
    for (int m = 0; m < 4; m++)
      #pragma unroll
      for (int kk = 0; kk < 2; kk++) a[m][kk] = frd(0, 0, wrow * 16 + m * 32, kk);
    #pragma unroll
    for (int n = 0; n < 2; n++)
      #pragma unroll
      for (int kk = 0; kk < 2; kk++) b[n][kk] = frd(0, 2, wcol * 16 + n * 64, kk);
    stg(1, 2, to);                               // B0 of odd tile (read ph5)
    BARRIER();
    __builtin_amdgcn_s_setprio(1);
    #pragma unroll
    for (int m = 0; m < 4; m++)
      #pragma unroll
      for (int n = 0; n < 2; n++)
        #pragma unroll
        for (int kk = 0; kk < 2; kk++)
          acc[m][n] = __builtin_amdgcn_mfma_f32_16x16x32_bf16(a[m][kk], b[n][kk], acc[m][n], 0, 0, 0);
    __builtin_amdgcn_s_setprio(0);
    BARRIER();
    // ---------- ph2: Q01 even (reads B1)
    #pragma unroll
    for (int n = 2; n < 4; n++)
      #pragma unroll
      for (int kk = 0; kk < 2; kk++) b[n][kk] = frd(0, 3, wcol * 16 + (n - 2) * 64, kk);
    if (pre) stg(0, 0, te + 2);
    BARRIER();
    __builtin_amdgcn_s_setprio(1);
    #pragma unroll
    for (int m = 0; m < 4; m++)
      #pragma unroll
      for (int n = 2; n < 4; n++)
        #pragma unroll
        for (int kk = 0; kk < 2; kk++)
          acc[m][n] = __builtin_amdgcn_mfma_f32_16x16x32_bf16(a[m][kk], b[n][kk], acc[m][n], 0, 0, 0);
    __builtin_amdgcn_s_setprio(0);
    BARRIER();
    // ---------- ph3: Q11 even (reads A1)
    #pragma unroll
    for (int m = 0; m < 4; m++)
      #pragma unroll
      for (int kk = 0; kk < 2; kk++) a[m][kk] = frd(0, 1, wrow * 16 + m * 32, kk);
    if (pre) stg(0, 3, te + 2);
    BARRIER();
    __builtin_amdgcn_s_setprio(1);
    #pragma unroll
    for (int m = 0; m < 4; m++)
      #pragma unroll
      for (int n = 2; n < 4; n++)
        #pragma unroll
        for (int kk = 0; kk < 2; kk++)
          acc[m + 4][n] = __builtin_amdgcn_mfma_f32_16x16x32_bf16(a[m][kk], b[n][kk], acc[m + 4][n], 0, 0, 0);
    __builtin_amdgcn_s_setprio(0);
    BARRIER();
    // ---------- ph4: Q10 even (re-reads B0)
    #pragma unroll
    for (int n = 0; n < 2; n++)
      #pragma unroll
      for (int kk = 0; kk < 2; kk++) b[n][kk] = frd(0, 2, wcol * 16 + n * 64, kk);
    if (pre) stg(0, 1, te + 2);
    BARRIER();
    __builtin_amdgcn_s_setprio(1);
    #pragma unroll
    for (int m = 0; m < 4; m++)
      #pragma unroll
      for (int n = 0; n < 2; n++)
        #pragma unroll
        for (int kk = 0; kk < 2; kk++)
          acc[m + 4][n] = __builtin_amdgcn_mfma_f32_16x16x32_bf16(a[m][kk], b[n][kk], acc[m + 4][n], 0, 0, 0);
    __builtin_amdgcn_s_setprio(0);
    if (pre) { VMC6(); } else { VMC0(); }        // tile(to) halves landed
    BARRIER();
    // ---------- ph5: Q00 odd
    #pragma unroll
    for (int m = 0; m < 4; m++)
      #pragma unroll
      for (int kk = 0; kk < 2; kk++) a[m][kk] = frd(1, 0, wrow * 16 + m * 32, kk);
    #pragma unroll
    for (int n = 0; n < 2; n++)
      #pragma unroll
      for (int kk = 0; kk < 2; kk++) b[n][kk] = frd(1, 2, wcol * 16 + n * 64, kk);
    if (pre) stg(0, 2, te + 2);
    BARRIER();
    __builtin_amdgcn_s_setprio(1);
    #pragma unroll
    for (int m = 0; m < 4; m++)
      #pragma unroll
      for (int n = 0; n < 2; n++)
        #pragma unroll
        for (int kk = 0; kk < 2; kk++)
          acc[m][n] = __builtin_amdgcn_mfma_f32_16x16x32_bf16(a[m][kk], b[n][kk], acc[m][n], 0, 0, 0);
    __builtin_amdgcn_s_setprio(0);
    BARRIER();
    // ---------- ph6: Q01 odd
    #pragma unroll
    for (int n = 2; n < 4; n++)
      #pragma unroll
      for (int kk = 0; kk < 2; kk++) b[n][kk] = frd(1, 3, wcol * 16 + (n - 2) * 64, kk);
    if (pre) stg(1, 0, to + 2);
    BARRIER();
    __builtin_amdgcn_s_setprio(1);
    #pragma unroll
    for (int m = 0; m < 4; m++)
      #pragma unroll
      for (int n = 2; n < 4; n++)
        #pragma unroll
        for (int kk = 0; kk < 2; kk++)
          acc[m][n] = __builtin_amdgcn_mfma_f32_16x16x32_bf16(a[m][kk], b[n][kk], acc[m][n], 0, 0, 0);
    __builtin_amdgcn_s_setprio(0);
    BARRIER();
    // ---------- ph7: Q11 odd
    #pragma unroll
    for (int m = 0; m < 4; m++)
      #pragma unroll
      for (int kk = 0; kk < 2; kk++) a[m][kk] = frd(1, 1, wrow * 16 + m * 32, kk);
    if (pre) stg(1, 3, to + 2);
    BARRIER();
    __builtin_amdgcn_s_setprio(1);
    #pragma unroll
    for (int m = 0; m < 4; m++)
      #pragma unroll
      for (int n = 2; n < 4; n++)
        #pragma unroll
        for (int kk = 0; kk < 2; kk++)
          acc[m + 4][n] = __builtin_amdgcn_mfma_f32_16x16x32_bf16(a[m][kk], b[n][kk], acc[m + 4][n], 0, 0, 0);
    __builtin_amdgcn_s_setprio(0);
    BARRIER();
    // ---------- ph8: Q10 odd
    #pragma unroll
    for (int n = 0; n < 2; n++)
      #pragma unroll
      for (int kk = 0; kk < 2; kk++) b[n][kk] = frd(1, 2, wcol * 16 + n * 64, kk);
    if (pre) stg(1, 1, to + 2);
    BARRIER();
    __builtin_amdgcn_s_setprio(1);
    #pragma unroll
    for (int m = 0; m < 4; m++)
      #pragma unroll
      for (int n = 0; n < 2; n++)
        #pragma unroll
        for (int kk = 0; kk < 2; kk++)
          acc[m + 4][n] = __builtin_amdgcn_mfma_f32_16x16x32_bf16(a[m][kk], b[n][kk], acc[m + 4][n], 0, 0, 0);
    __builtin_amdgcn_s_setprio(0);
    if (pre) { VMC6(); }                         // tile(te+2) halves landed
    BARRIER();
  }

  // epilogue
  #pragma unroll
  for (int m = 0; m < 8; m++){
    int rloc = ((m < 4) ? 0 : 128) + wrow * 16 + (m & 3) * 32 + (lane >> 4) * 4;
    #pragma unroll
    for (int j = 0; j < 4; j++){
      int rr = rloc + j;
      if (rr < nrows){
        size_t rowg = (size_t)(row0 + rr);
        #pragma unroll
        for (int n = 0; n < 4; n++){
          int cc = col0 + ((n < 2) ? 0 : 128) + wcol * 16 + (n & 1) * 64 + (lane & 15);
          float v = acc[m][n][j];
          if (GELU_EP){
            float g = v * 0.5f * (1.f + erff(v * 0.70710678118f));
            outFz[rowg * N + cc] = g;
            outB[rowg * N + cc] = f2bf(g);
          } else {
            outFz[rowg * N + cc] = v;
          }
        }
      }
    }
  }
}

// ---------------- combine: sum KSPLIT partials, weighted ----------------
__global__ __launch_bounds__(256) void combine_kernel(const float* __restrict__ yp,
                                                      const int* __restrict__ dest,
                                                      const float* __restrict__ tok_p,
                                                      float* __restrict__ out){
  int t = blockIdx.x;
  int d0 = dest[2*t], d1 = dest[2*t+1];
  float p0 = tok_p[2*t], p1 = tok_p[2*t+1];
  float4 r; r.x = 0.f; r.y = 0.f; r.z = 0.f; r.w = 0.f;
  #pragma unroll
  for (int s = 0; s < KSPLIT; s++){
    float4 a = ((const float4*)(yp + ((size_t)s * M_SLOT + d0) * H_DIM))[threadIdx.x];
    float4 b = ((const float4*)(yp + ((size_t)s * M_SLOT + d1) * H_DIM))[threadIdx.x];
    r.x += p0*a.x + p1*b.x; r.y += p0*a.y + p1*b.y;
    r.z += p0*a.z + p1*b.z; r.w += p0*a.w + p1*b.w;
  }
  ((float4*)(out + (size_t)t * H_DIM))[threadIdx.x] = r;
}

extern "C" void kernel_launch(void* const* d_in, const int* in_sizes, int n_in,
                              void* d_out, int out_size, void* d_ws, size_t ws_size,
                              hipStream_t stream) {
  const float* x  = (const float*)d_in[0];
  const float* rw = (const float*)d_in[1];
  const float* w1 = (const float*)d_in[2];
  const float* w2 = (const float*)d_in[3];
  float* out_mlp  = (float*)d_out;
  float* out_gelu = (float*)d_out + (size_t)T_TOK * H_DIM;

  char* ws = (char*)d_ws;
  // ypart aliases w1t (w1t dead after GEMM1; ypart written by GEMM2)
  u16*   w1t   = (u16*)(ws + 0);                 // [E][F][H] bf16, 64 MB
  float* ypart = (float*)(ws + 0);               // [2][M][H] f32,  32 MB (alias)
  u16*   w2t   = (u16*)(ws + 67108864);          // [E][H][F] bf16, 64 MB
  u16*   xg    = (u16*)(ws + 134217728);         // [M+256][H] bf16
  u16*   gb    = (u16*)(ws + 143130624);         // [M+256][F] bf16
  char*  small = ws + 178782208;
  int*   tok_e = (int*)(small);
  float* tok_p = (float*)(small + 16384);
  int*   dest  = (int*)(small + 32768);
  u32*   partial = (u32*)(small + 49152);
  u32*   baseb   = (u32*)(small + 51200);
  int4*  tiles   = (int4*)(small + 53248);
  int*   ntiles  = (int*)(small + 54272);

  router_kernel<<<T_TOK/4, 256, 0, stream>>>(x, rw, tok_e, tok_p);
  hist_kernel<<<M_SLOT/64, 64, 0, stream>>>(tok_e, partial);
  scan_kernel<<<1, 64, 0, stream>>>(partial, baseb, tiles, ntiles);
  scatter_kernel<<<M_SLOT/64, 64, 0, stream>>>(tok_e, baseb, dest);
  gather_kernel<<<M_SLOT, 256, 0, stream>>>(x, dest, xg);
  // transpose w1 immediately before GEMM1 (w1t L3-warm)
  transpose_cvt<H_DIM, F_DIM><<<dim3(F_DIM/64, H_DIM/64, E_NUM), 256, 0, stream>>>(w1, w1t);
  gemm8<F_DIM, H_DIM, 16, true><<<dim3(F_DIM/256, MAXTILES, 1), 512, 0, stream>>>(
      xg, w1t, tiles, ntiles, out_gelu, gb, 0);
  // transpose w2 immediately before GEMM2 (w2t L3-warm)
  transpose_cvt<F_DIM, H_DIM><<<dim3(H_DIM/64, F_DIM/64, E_NUM), 256, 0, stream>>>(w2, w2t);
  gemm8<H_DIM, F_DIM, 32, false><<<dim3(H_DIM/256, MAXTILES, KSPLIT), 512, 0, stream>>>(
      gb, w2t, tiles, ntiles, ypart, nullptr, (size_t)M_SLOT * H_DIM);
  combine_kernel<<<T_TOK, 256, 0, stream>>>(ypart, dest, tok_p, out_mlp);
}

// Round 11
// 236.033 us; speedup vs baseline: 1.1113x; 1.0637x over previous
//
#include <hip/hip_runtime.h>
#include <hip/hip_bf16.h>
#include <stdint.h>

typedef unsigned short u16;
typedef unsigned int u32;
typedef __attribute__((ext_vector_type(8))) short short8;
typedef __attribute__((ext_vector_type(4))) float f32x4;

#define T_TOK 2048
#define H_DIM 1024
#define F_DIM 4096
#define E_NUM 8
#define M_SLOT 4096
#define MAXTILES 40
#define KSPLIT 4

__device__ __forceinline__ u16 f2bf(float f){
  union { float f; u32 u; } v; v.f = f;
  return (u16)((v.u + 0x7FFFu + ((v.u >> 16) & 1u)) >> 16);
}

__device__ __forceinline__ void gload_lds16(const void* g, void* l){
  __builtin_amdgcn_global_load_lds(
      (const __attribute__((address_space(1))) u32*)g,
      (__attribute__((address_space(3))) u32*)l, 16, 0, 0);
}

// ---------------- router: logits = x @ rw, top2, softmax ----------------
__global__ __launch_bounds__(256) void router_kernel(
    const float* __restrict__ x, const float* __restrict__ rw,
    int* __restrict__ tok_e, float* __restrict__ tok_p){
  __shared__ float wlds[E_NUM * H_DIM];
  int tid = threadIdx.x;
  for (int i = tid; i < H_DIM * E_NUM; i += 256){
    int h = i >> 3, e = i & 7;
    wlds[e * H_DIM + h] = rw[i];
  }
  __syncthreads();
  int wave = tid >> 6, lane = tid & 63;
  int t = blockIdx.x * 4 + wave;
  const float* xr = x + (size_t)t * H_DIM;
  float acc[E_NUM];
  #pragma unroll
  for (int e = 0; e < E_NUM; e++) acc[e] = 0.f;
  for (int i = 0; i < H_DIM / 64; i++){
    float xv = xr[lane + 64 * i];
    #pragma unroll
    for (int e = 0; e < E_NUM; e++) acc[e] += xv * wlds[e * H_DIM + lane + 64 * i];
  }
  #pragma unroll
  for (int e = 0; e < E_NUM; e++){
    float r = acc[e];
    #pragma unroll
    for (int off = 32; off; off >>= 1) r += __shfl_xor(r, off, 64);
    acc[e] = r;
  }
  if (lane == 0){
    float l0 = acc[0]; int e0 = 0;
    #pragma unroll
    for (int e = 1; e < E_NUM; e++) if (acc[e] > l0){ l0 = acc[e]; e0 = e; }
    float l1 = -INFINITY; int e1 = 0;
    #pragma unroll
    for (int e = 0; e < E_NUM; e++) if (e != e0 && acc[e] > l1){ l1 = acc[e]; e1 = e; }
    float ex = expf(l1 - l0);
    float inv = 1.f / (1.f + ex);
    tok_e[2*t] = e0; tok_e[2*t+1] = e1;
    tok_p[2*t] = inv; tok_p[2*t+1] = ex * inv;
  }
}

// ---------------- histogram ----------------
__global__ void hist_kernel(const int* __restrict__ tok_e, u32* __restrict__ partial){
  int lane = threadIdx.x & 63;
  int m = blockIdx.x * 64 + lane;
  int e = tok_e[m];
  #pragma unroll
  for (int ee = 0; ee < E_NUM; ee++){
    unsigned long long mk = __ballot(e == ee);
    if (lane == ee) partial[blockIdx.x * E_NUM + ee] = (u32)__popcll(mk);
  }
}

// ---------------- scan + tile table (128-row tiles) ----------------
__global__ void scan_kernel(const u32* __restrict__ partial, u32* __restrict__ baseb,
                            int4* __restrict__ tiles, int* __restrict__ ntiles){
  int lane = threadIdx.x;  // 64 threads
  u32 exc[E_NUM], tot[E_NUM];
  #pragma unroll
  for (int e = 0; e < E_NUM; e++){
    u32 v = partial[lane * E_NUM + e];
    u32 own = v;
    #pragma unroll
    for (int off = 1; off < 64; off <<= 1){
      u32 tu = __shfl_up(v, off, 64);
      if (lane >= off) v += tu;
    }
    exc[e] = v - own;
    tot[e] = __shfl(v, 63, 64);
  }
  u32 offs[E_NUM + 1]; offs[0] = 0;
  #pragma unroll
  for (int e = 0; e < E_NUM; e++) offs[e+1] = offs[e] + tot[e];
  #pragma unroll
  for (int e = 0; e < E_NUM; e++) baseb[lane * E_NUM + e] = offs[e] + exc[e];
  if (lane == 0){
    int nt = 0;
    for (int e = 0; e < E_NUM; e++){
      int cnt = (int)tot[e];
      for (int r0 = 0; r0 < cnt; r0 += 128){
        tiles[nt] = make_int4((int)offs[e] + r0, min(128, cnt - r0), e, 0);
        nt++;
      }
    }
    *ntiles = nt;
  }
}

// ---------------- scatter ----------------
__global__ void scatter_kernel(const int* __restrict__ tok_e, const u32* __restrict__ baseb,
                               int* __restrict__ dest){
  int lane = threadIdx.x & 63;
  int m = blockIdx.x * 64 + lane;
  int e = tok_e[m];
  unsigned long long eq = 0;
  #pragma unroll
  for (int ee = 0; ee < E_NUM; ee++){
    unsigned long long mk = __ballot(e == ee);
    if (e == ee) eq = mk;
  }
  u32 rank = (u32)__popcll(eq & ((1ull << lane) - 1ull));
  dest[m] = (int)(baseb[blockIdx.x * E_NUM + e] + rank);
}

// ---------------- transpose body: [E][R][C] f32 -> [E][C][R] bf16 ----------------
template<int R, int C>
__device__ __forceinline__ void transpose_body(const float* __restrict__ in,
                                               u16* __restrict__ out,
                                               int cx, int ry, int e,
                                               u16 (*tile)[66]){
  const float* ip = in + (size_t)e * R * C;
  u16* op = out + (size_t)e * R * C;
  int c0 = cx * 64, r0 = ry * 64;
  int tr = threadIdx.x >> 4, tc = threadIdx.x & 15;
  #pragma unroll
  for (int i = 0; i < 4; i++){
    int r = tr + i * 16;
    float4 v = *(const float4*)(ip + (size_t)(r0 + r) * C + c0 + tc * 4);
    tile[r][tc*4+0] = f2bf(v.x); tile[r][tc*4+1] = f2bf(v.y);
    tile[r][tc*4+2] = f2bf(v.z); tile[r][tc*4+3] = f2bf(v.w);
  }
  __syncthreads();
  #pragma unroll
  for (int i = 0; i < 4; i++){
    int c = tr + i * 16;
    ushort4 o;
    o.x = tile[tc*4+0][c]; o.y = tile[tc*4+1][c];
    o.z = tile[tc*4+2][c]; o.w = tile[tc*4+3][c];
    *(ushort4*)(op + (size_t)(c0 + c) * R + r0 + tc * 4) = o;
  }
}

// ---------------- gemm97 body (r5 proven): 128x128, BK=64, 4 waves ----------
// A [*][KSTRIDE] bf16; Bt [E][N][KSTRIDE] bf16. 32 KB LDS, XOR swizzle.
template<int N, int KSTRIDE, int NT, bool GELU_EP>
__device__ __forceinline__ void gemm_body(
    u16* As, u16* Bs,
    const u16* __restrict__ A, const u16* __restrict__ Bt,
    const int4* __restrict__ tiles, const int* __restrict__ ntiles_p,
    float* __restrict__ outF, u16* __restrict__ outB, size_t zstride,
    int colBlk, int tileBlk, int z){
  if (tileBlk >= *ntiles_p) return;
  int4 ti = tiles[tileBlk];
  int row0 = ti.x, nrows = ti.y, e = ti.z;
  int col0 = colBlk * 128;
  size_t kofs = (size_t)z * ((size_t)NT * 64);
  const u16* Be = Bt + (size_t)e * N * KSTRIDE;
  float* outFz = outF + (size_t)z * zstride;

  int lane = threadIdx.x & 63, wid = threadIdx.x >> 6;
  int wr = wid >> 1, wc = wid & 1;

  f32x4 acc[4][4];
  #pragma unroll
  for (int m = 0; m < 4; m++)
    #pragma unroll
    for (int n = 0; n < 4; n++) acc[m][n] = (f32x4)0.f;

  int srow = (wid << 3) + (lane >> 3);
  int skx  = ((lane & 7) * 16) ^ ((lane >> 3) << 4);

  for (int kt = 0; kt < NT; kt++){
    size_t kb = kofs + (size_t)kt * 64;
    #pragma unroll
    for (int i = 0; i < 4; i++){
      int row = i * 32 + srow;
      gload_lds16((const char*)(A  + (size_t)(row0 + row) * KSTRIDE + kb) + skx,
                  As + i * 2048 + wid * 512);
      gload_lds16((const char*)(Be + (size_t)(col0 + row) * KSTRIDE + kb) + skx,
                  Bs + i * 2048 + wid * 512);
    }
    __syncthreads();
    short8 a[4][2], b[4][2];
    #pragma unroll
    for (int m = 0; m < 4; m++){
      int row = wr * 64 + m * 16 + (lane & 15);
      #pragma unroll
      for (int kk = 0; kk < 2; kk++){
        int byte_ = row * 128 + ((kk * 64 + (lane >> 4) * 16) ^ ((row & 7) << 4));
        a[m][kk] = *(const short8*)((const char*)As + byte_);
      }
    }
    #pragma unroll
    for (int n = 0; n < 4; n++){
      int row = wc * 64 + n * 16 + (lane & 15);
      #pragma unroll
      for (int kk = 0; kk < 2; kk++){
        int byte_ = row * 128 + ((kk * 64 + (lane >> 4) * 16) ^ ((row & 7) << 4));
        b[n][kk] = *(const short8*)((const char*)Bs + byte_);
      }
    }
    #pragma unroll
    for (int m = 0; m < 4; m++)
      #pragma unroll
      for (int n = 0; n < 4; n++)
        #pragma unroll
        for (int kk = 0; kk < 2; kk++)
          acc[m][n] = __builtin_amdgcn_mfma_f32_16x16x32_bf16(a[m][kk], b[n][kk], acc[m][n], 0, 0, 0);
    __syncthreads();
  }

  #pragma unroll
  for (int m = 0; m < 4; m++){
    int rloc = wr * 64 + m * 16 + (lane >> 4) * 4;
    #pragma unroll
    for (int j = 0; j < 4; j++){
      int rr = rloc + j;
      if (rr < nrows){
        size_t rowg = (size_t)(row0 + rr);
        #pragma unroll
        for (int n = 0; n < 4; n++){
          int cc = col0 + wc * 64 + n * 16 + (lane & 15);
          float v = acc[m][n][j];
          if (GELU_EP){
            float g = v * 0.5f * (1.f + erff(v * 0.70710678118f));
            outFz[rowg * N + cc] = g;
            outB[rowg * N + cc] = f2bf(g);
          } else {
            outFz[rowg * N + cc] = v;
          }
        }
      }
    }
  }
}

// ---------------- fused: gather (bid<4096) + transpose-w1 (8192 blocks) ----
__global__ __launch_bounds__(256) void gather_tw1_kernel(
    const float* __restrict__ x, const int* __restrict__ dest,
    u16* __restrict__ xg, const float* __restrict__ w1, u16* __restrict__ w1t){
  __shared__ __align__(16) u16 tile[64][66];
  int bid = blockIdx.x;
  if (bid < M_SLOT){
    int d = dest[bid];
    const float4* xr = (const float4*)(x + (size_t)(bid >> 1) * H_DIM);
    float4 v = xr[threadIdx.x];
    ushort4 o;
    o.x = f2bf(v.x); o.y = f2bf(v.y); o.z = f2bf(v.z); o.w = f2bf(v.w);
    ((ushort4*)(xg + (size_t)d * H_DIM))[threadIdx.x] = o;
  } else {
    int tb = bid - M_SLOT;              // 8192 blocks: w1 [E][1024][4096] -> w1t
    transpose_body<H_DIM, F_DIM>(w1, w1t, tb & 63, (tb >> 6) & 15, tb >> 10, tile);
  }
}

// ---------------- fused: GEMM1 (bid<1280) + transpose-w2 (8192 blocks) ----
__global__ __launch_bounds__(256, 4) void gemm1_tw2_kernel(
    const u16* __restrict__ xg, const u16* __restrict__ w1t,
    const int4* __restrict__ tiles, const int* __restrict__ ntiles,
    float* __restrict__ out_gelu, u16* __restrict__ gb,
    const float* __restrict__ w2, u16* __restrict__ w2t){
  __shared__ __align__(16) u16 sh[2 * 128 * 64];   // 32 KB union
  int bid = blockIdx.x;
  if (bid < 32 * MAXTILES){
    gemm_body<F_DIM, H_DIM, 16, true>(sh, sh + 8192, xg, w1t, tiles, ntiles,
                                      out_gelu, gb, 0, bid & 31, bid >> 5, 0);
  } else {
    int tb = bid - 32 * MAXTILES;       // 8192 blocks: w2 [E][4096][1024] -> w2t
    transpose_body<F_DIM, H_DIM>(w2, w2t, tb & 15, (tb >> 4) & 63, tb >> 10,
                                 (u16(*)[66])sh);
  }
}

// ---------------- GEMM2 standalone (split-K=4) ----------------
__global__ __launch_bounds__(256, 4) void gemm2_kernel(
    const u16* __restrict__ gb, const u16* __restrict__ w2t,
    const int4* __restrict__ tiles, const int* __restrict__ ntiles,
    float* __restrict__ ypart){
  __shared__ __align__(16) u16 sh[2 * 128 * 64];
  gemm_body<H_DIM, F_DIM, 16, false>(sh, sh + 8192, gb, w2t, tiles, ntiles,
                                     ypart, nullptr, (size_t)M_SLOT * H_DIM,
                                     blockIdx.x, blockIdx.y, blockIdx.z);
}

// ---------------- combine: sum KSPLIT partials, weighted ----------------
__global__ __launch_bounds__(256) void combine_kernel(const float* __restrict__ yp,
                                                      const int* __restrict__ dest,
                                                      const float* __restrict__ tok_p,
                                                      float* __restrict__ out){
  int t = blockIdx.x;
  int d0 = dest[2*t], d1 = dest[2*t+1];
  float p0 = tok_p[2*t], p1 = tok_p[2*t+1];
  float4 r; r.x = 0.f; r.y = 0.f; r.z = 0.f; r.w = 0.f;
  #pragma unroll
  for (int s = 0; s < KSPLIT; s++){
    float4 a = ((const float4*)(yp + ((size_t)s * M_SLOT + d0) * H_DIM))[threadIdx.x];
    float4 b = ((const float4*)(yp + ((size_t)s * M_SLOT + d1) * H_DIM))[threadIdx.x];
    r.x += p0*a.x + p1*b.x; r.y += p0*a.y + p1*b.y;
    r.z += p0*a.z + p1*b.z; r.w += p0*a.w + p1*b.w;
  }
  ((float4*)(out + (size_t)t * H_DIM))[threadIdx.x] = r;
}

extern "C" void kernel_launch(void* const* d_in, const int* in_sizes, int n_in,
                              void* d_out, int out_size, void* d_ws, size_t ws_size,
                              hipStream_t stream) {
  const float* x  = (const float*)d_in[0];
  const float* rw = (const float*)d_in[1];
  const float* w1 = (const float*)d_in[2];
  const float* w2 = (const float*)d_in[3];
  float* out_mlp  = (float*)d_out;
  float* out_gelu = (float*)d_out + (size_t)T_TOK * H_DIM;

  char* ws = (char*)d_ws;
  // ypart [4][M][H] f32 (64 MB) aliases w1t (dead after GEMM1)
  u16*   w1t   = (u16*)(ws + 0);                 // [E][F][H] bf16, 64 MB
  float* ypart = (float*)(ws + 0);               // alias
  u16*   w2t   = (u16*)(ws + 67108864);          // [E][H][F] bf16, 64 MB
  u16*   xg    = (u16*)(ws + 134217728);         // [M+128][H] bf16
  u16*   gb    = (u16*)(ws + 143130624);         // [M+128][F] bf16
  char*  small = ws + 178782208;
  int*   tok_e = (int*)(small);
  float* tok_p = (float*)(small + 16384);
  int*   dest  = (int*)(small + 32768);
  u32*   partial = (u32*)(small + 49152);
  u32*   baseb   = (u32*)(small + 51200);
  int4*  tiles   = (int4*)(small + 53248);
  int*   ntiles  = (int*)(small + 54272);

  router_kernel<<<T_TOK/4, 256, 0, stream>>>(x, rw, tok_e, tok_p);
  hist_kernel<<<M_SLOT/64, 64, 0, stream>>>(tok_e, partial);
  scan_kernel<<<1, 64, 0, stream>>>(partial, baseb, tiles, ntiles);
  scatter_kernel<<<M_SLOT/64, 64, 0, stream>>>(tok_e, baseb, dest);
  // gather + transpose-w1 fused (independent work, one launch)
  gather_tw1_kernel<<<M_SLOT + 8192, 256, 0, stream>>>(x, dest, xg, w1, w1t);
  // GEMM1 + transpose-w2 fused: GEMM blocks dispatch first, transpose blocks
  // stream in the HBM-BW headroom of the latency-bound GEMM
  gemm1_tw2_kernel<<<32 * MAXTILES + 8192, 256, 0, stream>>>(
      xg, w1t, tiles, ntiles, out_gelu, gb, w2, w2t);
  // GEMM2: [M,4096] @ w2t, split-K=4
  gemm2_kernel<<<dim3(H_DIM/128, MAXTILES, KSPLIT), 256, 0, stream>>>(
      gb, w2t, tiles, ntiles, ypart);
  combine_kernel<<<T_TOK, 256, 0, stream>>>(ypart, dest, tok_p, out_mlp);
}